// Round 5
// baseline (109123.010 us; speedup 1.0000x reference)
//
#include <hip/hip_runtime.h>
#include <hip/hip_bf16.h>

// MogrifierRNN on MI355X — Round 5: fp32 output storage.
// Case closed on dtypes: R3 and R4 produced BIT-IDENTICAL absmax (1.289062)
// even though R4 bf16-rounded every input -> the rounding was a no-op -> the
// fp32-stored input VALUES are already bf16-cast (low mantissa halves zero).
// Hence: storage is fp32 everywhere (matches R1/R2's NaN on 16-bit reads),
// the bf16-floor threshold comes from the value cast, and d_out is FLOAT*
// (reference output dtype fp32). R3/R4 failed only because they wrote 16-bit
// bf16 into the fp32 output buffer (half-filled, pair-packed -> absmax
// = max|h|+max|ref| = 1.289, deterministic). This round: identical compute,
// fp32 output writes.

constexpr int SEQ   = 512;
constexpr int BATCH = 128;
constexpr int KR    = 256;          // low-rank
constexpr int BN    = BATCH * 512;  // 65536

__device__ __forceinline__ float sigm(float z) { return 1.f / (1.f + expf(-z)); }

// load fp32, round to bf16 (RNE), return fp32. Idempotent on the dataset's
// pre-bf16-cast values; keeps us exactly on the reference's value grid.
__device__ __forceinline__ float ldbf(const float* __restrict__ p, size_t i) {
  unsigned u = __float_as_uint(p[i]);
  u = (u + 0x7FFFu + ((u >> 16) & 1u)) & 0xFFFF0000u;
  return __uint_as_float(u);
}

// outT[p][a][bcol] = sum_r right[p][r][a] * left[p][bcol][r]   (fp32 acc)
// Q: QdT[p][n][m] = Q[p][m][n];  R: RdT[p][m][n] = R[p][n][m]
__global__ void qr_precompute(const float* __restrict__ right,
                              const float* __restrict__ left,
                              float* __restrict__ outT) {
  int flat = blockIdx.x * 256 + threadIdx.x;   // 2*512*512 threads
  int p    = flat >> 18;
  int a    = (flat >> 9) & 511;
  int bcol = flat & 511;
  size_t rbase = (size_t)p * KR * 512;
  size_t lbase = (size_t)p * 512 * KR + (size_t)bcol * KR;
  float acc = 0.f;
  for (int r = 0; r < KR; r++)
    acc += ldbf(right, rbase + (size_t)r * 512 + a) * ldbf(left, lbase + r);
  outT[flat] = acc;
}

// Stage A: out[b][j] = 2*sigmoid(sum_k act[b][k]*WT[k][j]) * x[xoff + b*512+j]
// grid (32 j-blocks, 8 b-tiles), block 256: tile [16 b x 16 j], 1 out/thread.
__global__ void mog_stage_x(const float* __restrict__ act,
                            const float* __restrict__ WT,
                            const float* __restrict__ x, size_t xoff,
                            float* __restrict__ out) {
  int jl = threadIdx.x & 15, bl = threadIdx.x >> 4;
  int j = blockIdx.x * 16 + jl;
  int b = blockIdx.y * 16 + bl;
  const float* a = act + (size_t)b * 512;
  float acc = 0.f;
#pragma unroll 8
  for (int k = 0; k < 512; k++)
    acc += a[k] * WT[(size_t)k * 512 + j];
  size_t idx = (size_t)b * 512 + j;
  out[idx] = 2.f * sigm(acc) * ldbf(x, xoff + idx);
}

// Stages B-D: src is a ws fp32 buffer; src/out may alias elementwise
// (same index per thread) -> no __restrict__ on them.
__global__ void mog_stage(const float* __restrict__ act,
                          const float* __restrict__ WT,
                          const float* src, float* out) {
  int jl = threadIdx.x & 15, bl = threadIdx.x >> 4;
  int j = blockIdx.x * 16 + jl;
  int b = blockIdx.y * 16 + bl;
  const float* a = act + (size_t)b * 512;
  float acc = 0.f;
#pragma unroll 8
  for (int k = 0; k < 512; k++)
    acc += a[k] * WT[(size_t)k * 512 + j];
  size_t idx = (size_t)b * 512 + j;
  out[idx] = 2.f * sigm(acc) * src[idx];
}

// Fused gates + LSTM. grid (32 n-blocks, 8 b-tiles), block 256.
// gates[b][g*512+n] = sum_k xx[b][k]*Wih[g*512+n][k] + h[b][k]*Whh[g*512+n][k]
__global__ void gates_lstm(const float* __restrict__ xx, const float* __restrict__ h,
                           const float* __restrict__ Wih, const float* __restrict__ Whh,
                           const float* __restrict__ bih, const float* __restrict__ bhh,
                           float* __restrict__ c, float* __restrict__ hn,
                           float* __restrict__ y) {
  int nl = threadIdx.x & 15, bl = threadIdx.x >> 4;
  int n = blockIdx.x * 16 + nl;
  int b = blockIdx.y * 16 + bl;
  const float* xa = xx + (size_t)b * 512;
  const float* ha = h + (size_t)b * 512;
  float acc[4];
#pragma unroll
  for (int g = 0; g < 4; g++) {
    size_t wrow = (size_t)(g * 512 + n) * 512;
    float s = 0.f;
#pragma unroll 4
    for (int k = 0; k < 512; k++)
      s += xa[k] * ldbf(Wih, wrow + k) + ha[k] * ldbf(Whh, wrow + k);
    acc[g] = s + ldbf(bih, g * 512 + n) + ldbf(bhh, g * 512 + n);
  }
  float ig = sigm(acc[0]), fg = sigm(acc[1]), og = sigm(acc[3]);
  float gg = tanhf(acc[2]);
  size_t idx = (size_t)b * 512 + n;
  float cv = fg * c[idx] + ig * gg;
  float hv = og * tanhf(cv);
  c[idx] = cv;
  hn[idx] = hv;
  y[idx] = hv;                       // fp32 output
}

// write final (h, c) to the output tail (fp32)
__global__ void finalize(const float* __restrict__ h, const float* __restrict__ c,
                         float* __restrict__ tail) {
  int flat = blockIdx.x * 256 + threadIdx.x;  // 65536
  tail[flat] = h[flat];
  tail[BN + flat] = c[flat];
}

extern "C" void kernel_launch(void* const* d_in, const int* in_sizes, int n_in,
                              void* d_out, int out_size, void* d_ws, size_t ws_size,
                              hipStream_t stream) {
  const float* x   = (const float*)d_in[0];
  const float* Ql  = (const float*)d_in[1];
  const float* Qr  = (const float*)d_in[2];
  const float* Rl  = (const float*)d_in[3];
  const float* Rr  = (const float*)d_in[4];
  const float* Wih = (const float*)d_in[5];
  const float* Whh = (const float*)d_in[6];
  const float* bih = (const float*)d_in[7];
  const float* bhh = (const float*)d_in[8];
  float* out = (float*)d_out;

  // ws layout: QdT [2][512][512] f32, RdT [2][512][512] f32,
  //            hA, hB, cbuf, xxb: [128][512] f32.  Total 5,242,880 B.
  constexpr size_t QR_ELEMS = 2ull * 512 * 512;
  constexpr size_t FLOATS = 2 * QR_ELEMS + 4ull * (size_t)BN;
  constexpr size_t NEED = FLOATS * sizeof(float);
  if (ws_size < NEED) return;  // diagnostic signature: absmax 0.711

  float* ws   = (float*)d_ws;
  float* QdT  = ws;
  float* RdT  = QdT + QR_ELEMS;
  float* hA   = RdT + QR_ELEMS;
  float* hB   = hA + BN;
  float* cbuf = hB + BN;
  float* xxb  = cbuf + BN;

  qr_precompute<<<2048, 256, 0, stream>>>(Qr, Ql, QdT);
  qr_precompute<<<2048, 256, 0, stream>>>(Rr, Rl, RdT);
  hipMemsetAsync(hA, 0, BN * sizeof(float), stream);    // h0 = 0
  hipMemsetAsync(cbuf, 0, BN * sizeof(float), stream);  // c0 = 0

  dim3 mgrid(32, 8);
  for (int t = 0; t < SEQ; t++) {
    float* cur = (t & 1) ? hB : hA;   // h carry in (mogrified in place)
    float* nxt = (t & 1) ? hA : hB;   // h carry out (LSTM output)
    mog_stage_x<<<mgrid, 256, 0, stream>>>(cur, QdT, x, (size_t)t * BN, xxb);
    mog_stage  <<<mgrid, 256, 0, stream>>>(xxb, RdT,             cur, cur);
    mog_stage  <<<mgrid, 256, 0, stream>>>(cur, QdT + 512 * 512, xxb, xxb);
    mog_stage  <<<mgrid, 256, 0, stream>>>(xxb, RdT + 512 * 512, cur, cur);
    gates_lstm <<<mgrid, 256, 0, stream>>>(xxb, cur, Wih, Whh, bih, bhh,
                                           cbuf, nxt, out + (size_t)t * BN);
  }
  // after t=511 (odd), final h landed in hA
  finalize<<<256, 256, 0, stream>>>(hA, cbuf, out + (size_t)SEQ * BN);
}